// Round 1
// baseline (85.191 us; speedup 1.0000x reference)
//
#include <hip/hip_runtime.h>

#define BM 64
#define BN 64
#define BKK 16
#define TM 4
#define TN 4

#define TT 2048
#define CC 512
#define CH 32
#define NCH 64   // TT / CH

// C[M,N] = A[M,K] @ B[K,N]; A addressed as A[m*lda + acol0 + k], B as B[k*ldb + bcol0 + n]
__global__ __launch_bounds__(256) void gemm_f32(
    const float* __restrict__ A, int lda, int acol0,
    const float* __restrict__ B, int ldb, int bcol0,
    float* __restrict__ C, int M, int N, int K)
{
    __shared__ float As[BKK][BM + 1];   // +1 pad: transposed store, conflict-free
    __shared__ float Bs[BKK][BN];

    const int tid = threadIdx.x;
    const int tx = tid & 15;      // n direction (coalesced C writes)
    const int ty = tid >> 4;      // m direction
    const int bm = blockIdx.y * BM;
    const int bn = blockIdx.x * BN;

    float acc[TM][TN];
    #pragma unroll
    for (int i = 0; i < TM; i++)
        #pragma unroll
        for (int j = 0; j < TN; j++) acc[i][j] = 0.f;

    const int arow = tid >> 2;    // 0..63
    const int akq  = tid & 3;     // k-quad
    const int brow = tid >> 4;    // 0..15
    const int bnq  = tid & 15;    // n-quad

    for (int k0 = 0; k0 < K; k0 += BKK) {
        // A tile 64x16, loaded as float4 along K, stored transposed
        const float* ap = A + (size_t)(bm + arow) * lda + acol0 + k0 + akq * 4;
        float4 av = *reinterpret_cast<const float4*>(ap);
        As[akq * 4 + 0][arow] = av.x;
        As[akq * 4 + 1][arow] = av.y;
        As[akq * 4 + 2][arow] = av.z;
        As[akq * 4 + 3][arow] = av.w;
        // B tile 16x64, float4 along N
        const float* bp = B + (size_t)(k0 + brow) * ldb + bcol0 + bn + bnq * 4;
        float4 bv = *reinterpret_cast<const float4*>(bp);
        *reinterpret_cast<float4*>(&Bs[brow][bnq * 4]) = bv;
        __syncthreads();

        #pragma unroll
        for (int k = 0; k < BKK; ++k) {
            float a[TM], b[TN];
            #pragma unroll
            for (int i = 0; i < TM; i++) a[i] = As[k][ty * TM + i];
            float4 bb = *reinterpret_cast<const float4*>(&Bs[k][tx * TN]);
            b[0] = bb.x; b[1] = bb.y; b[2] = bb.z; b[3] = bb.w;
            #pragma unroll
            for (int i = 0; i < TM; i++)
                #pragma unroll
                for (int j = 0; j < TN; j++)
                    acc[i][j] = fmaf(a[i], b[j], acc[i][j]);
        }
        __syncthreads();
    }

    #pragma unroll
    for (int i = 0; i < TM; i++) {
        float4 o;
        o.x = acc[i][0]; o.y = acc[i][1]; o.z = acc[i][2]; o.w = acc[i][3];
        *reinterpret_cast<float4*>(&C[(size_t)(bm + ty * TM + i) * N + bn + tx * TN]) = o;
    }
}

// pass 1: per-(b, chunk) column sums of u over its CH rows
__global__ __launch_bounds__(512) void partial_sums(const float* __restrict__ u,
                                                    float* __restrict__ part)
{
    const int b  = blockIdx.x >> 6;   // / NCH
    const int ch = blockIdx.x & (NCH - 1);
    const int j  = threadIdx.x;       // 0..511
    const float* p = u + ((size_t)b * TT + (size_t)ch * CH) * CC + j;
    float s = 0.f;
    #pragma unroll 8
    for (int t = 0; t < CH; t++) s += p[(size_t)t * CC];
    part[((size_t)b * NCH + ch) * CC + j] = s;
}

// pass 2: exclusive prefix over chunks, per (b, j) column. 1024 threads total.
__global__ __launch_bounds__(512) void scan_parts(float* __restrict__ part)
{
    const int idx = blockIdx.x * blockDim.x + threadIdx.x; // b*512 + j
    const int b = idx >> 9;
    const int j = idx & 511;
    float run = 0.f;
    for (int c = 0; c < NCH; c++) {
        size_t off = ((size_t)b * NCH + c) * CC + j;
        float t = part[off];
        part[off] = run;
        run += t;
    }
}

// pass 3: y[b,t,j] = (prefix + local running sum) / (t+1)
__global__ __launch_bounds__(512) void finalize(const float* __restrict__ u,
                                                const float* __restrict__ part,
                                                float* __restrict__ y)
{
    const int b  = blockIdx.x >> 6;
    const int ch = blockIdx.x & (NCH - 1);
    const int j  = threadIdx.x;
    float run = part[((size_t)b * NCH + ch) * CC + j];
    const float* p = u + ((size_t)b * TT + (size_t)ch * CH) * CC + j;
    float*       q = y + ((size_t)b * TT + (size_t)ch * CH) * CC + j;
    #pragma unroll 4
    for (int t = 0; t < CH; t++) {
        run += p[(size_t)t * CC];
        q[(size_t)t * CC] = run * (1.0f / (float)(ch * CH + t + 1));
    }
}

extern "C" void kernel_launch(void* const* d_in, const int* in_sizes, int n_in,
                              void* d_out, int out_size, void* d_ws, size_t ws_size,
                              hipStream_t stream)
{
    const float* x      = (const float*)d_in[0];   // (2, 2048, 512)
    const float* w_attn = (const float*)d_in[1];   // (512, 1536); V part = cols [1024,1536)
    const float* w_proj = (const float*)d_in[2];   // (512, 512)
    float* y = (float*)d_out;                      // (2, 2048, 512)

    float* wc   = (float*)d_ws;                    // 512*512
    float* u    = wc + 512 * 512;                  // 4096*512
    float* part = u + 4096 * 512;                  // 2*64*512

    dim3 blk(256);
    // w_c = w_v @ w_proj   (512x512x512)
    gemm_f32<<<dim3(512 / BN, 512 / BM), blk, 0, stream>>>(
        w_attn, 1536, 1024, w_proj, 512, 0, wc, 512, 512, 512);
    // u = x @ w_c          (4096x512x512)
    gemm_f32<<<dim3(512 / BN, 4096 / BM), blk, 0, stream>>>(
        x, 512, 0, wc, 512, 0, u, 4096, 512, 512);
    // causal running mean along t
    partial_sums<<<2 * NCH, 512, 0, stream>>>(u, part);
    scan_parts<<<2, 512, 0, stream>>>(part);
    finalize<<<2 * NCH, 512, 0, stream>>>(u, part, y);
}

// Round 2
// 39.626 us; speedup vs baseline: 2.1498x; 2.1498x over previous
//
#include <hip/hip_runtime.h>

typedef __bf16 bf16x8 __attribute__((ext_vector_type(8)));
typedef float  f32x4  __attribute__((ext_vector_type(4)));

__device__ __forceinline__ unsigned short f2bf(float f) {
    unsigned int u = __float_as_uint(f);
    u += 0x7FFF + ((u >> 16) & 1);          // round-to-nearest-even
    return (unsigned short)(u >> 16);
}

#define GLD_LDS16(gptr, lptr) \
    __builtin_amdgcn_global_load_lds((const __attribute__((address_space(1))) void*)(gptr), \
                                     (__attribute__((address_space(3))) void*)(lptr), 16, 0, 0)

// C[m][n] = sum_k A[m][k] * Bt[n][k].  A:[M][512] bf16, Bt:[N][512] bf16, K=512.
// EPI=0: Cout = float[M][512] row-major.  EPI=1: Cout = ushort bf16 [N][512] TRANSPOSED (C^T).
// Tile 64x64, BK=64, 4 waves (2m x 2n), wave tile 32x32 = 2x2 frags of 16x16x32.
template<int EPI>
__global__ __launch_bounds__(256) void gemm_bf16(
    const unsigned short* __restrict__ A,
    const unsigned short* __restrict__ Bt,
    void* __restrict__ Cout)
{
    __shared__ unsigned short lds[2][2][64 * 64];   // [buf][A/B][row*64+col] 32 KiB

    const int tid  = threadIdx.x;
    const int lane = tid & 63;
    const int w    = tid >> 6;          // 0..3
    const int wm   = w >> 1, wn = w & 1;
    const int bm   = blockIdx.y * 64;
    const int bn   = blockIdx.x * 64;

    // ---- staging addresses: tile row = w*16 + inst*8 + (lane>>3), 16B chunk pre-swizzled
    const int srow   = w * 16 + (lane >> 3);
    const int schunk = (lane & 7) ^ (lane >> 3);    // inverse-swizzle on SOURCE (involution)
    const unsigned short* gA0 = A  + (size_t)(bm + srow    ) * 512 + schunk * 8;
    const unsigned short* gA1 = A  + (size_t)(bm + srow + 8) * 512 + schunk * 8;
    const unsigned short* gB0 = Bt + (size_t)(bn + srow    ) * 512 + schunk * 8;
    const unsigned short* gB1 = Bt + (size_t)(bn + srow + 8) * 512 + schunk * 8;

    // ---- fragment read byte-offsets (swizzled on READ with the same involution)
    const int arow = lane & 15;
    const int kg   = lane >> 4;          // k-group 0..3
    int offA[2][2], offB[2][2];
    #pragma unroll
    for (int f = 0; f < 2; ++f)
        #pragma unroll
        for (int kk = 0; kk < 2; ++kk) {
            offA[f][kk] = (wm * 32 + f * 16 + arow) * 128 + (((kk * 4 + kg) ^ (arow & 7)) << 4);
            offB[f][kk] = (wn * 32 + f * 16 + arow) * 128 + (((kk * 4 + kg) ^ (arow & 7)) << 4);
        }

    f32x4 acc[2][2] = {};

    auto stage = [&](int buf, int kt) {
        const int k0 = kt * 64;
        unsigned short* la = &lds[buf][0][0];
        unsigned short* lb = &lds[buf][1][0];
        GLD_LDS16(gA0 + k0, la + (w * 16 + 0) * 64);
        GLD_LDS16(gA1 + k0, la + (w * 16 + 8) * 64);
        GLD_LDS16(gB0 + k0, lb + (w * 16 + 0) * 64);
        GLD_LDS16(gB1 + k0, lb + (w * 16 + 8) * 64);
    };

    stage(0, 0);
    asm volatile("s_waitcnt vmcnt(0)" ::: "memory");
    __syncthreads();

    #pragma unroll
    for (int kt = 0; kt < 8; ++kt) {
        const int buf = kt & 1;
        if (kt < 7) stage(buf ^ 1, kt + 1);          // issue next-tile loads first (T3-min)
        const char* la = (const char*)&lds[buf][0][0];
        const char* lb = (const char*)&lds[buf][1][0];
        #pragma unroll
        for (int kk = 0; kk < 2; ++kk) {
            bf16x8 a0 = *(const bf16x8*)(la + offA[0][kk]);
            bf16x8 a1 = *(const bf16x8*)(la + offA[1][kk]);
            bf16x8 b0 = *(const bf16x8*)(lb + offB[0][kk]);
            bf16x8 b1 = *(const bf16x8*)(lb + offB[1][kk]);
            acc[0][0] = __builtin_amdgcn_mfma_f32_16x16x32_bf16(a0, b0, acc[0][0], 0, 0, 0);
            acc[0][1] = __builtin_amdgcn_mfma_f32_16x16x32_bf16(a0, b1, acc[0][1], 0, 0, 0);
            acc[1][0] = __builtin_amdgcn_mfma_f32_16x16x32_bf16(a1, b0, acc[1][0], 0, 0, 0);
            acc[1][1] = __builtin_amdgcn_mfma_f32_16x16x32_bf16(a1, b1, acc[1][1], 0, 0, 0);
        }
        asm volatile("s_waitcnt vmcnt(0)" ::: "memory");
        __syncthreads();
    }

    #pragma unroll
    for (int fm = 0; fm < 2; ++fm)
        #pragma unroll
        for (int fn = 0; fn < 2; ++fn) {
            const int row0 = bm + wm * 32 + fm * 16 + kg * 4;
            const int col  = bn + wn * 32 + fn * 16 + arow;
            if (EPI == 0) {
                float* C = (float*)Cout;
                #pragma unroll
                for (int r = 0; r < 4; ++r)
                    C[(size_t)(row0 + r) * 512 + col] = acc[fm][fn][r];
            } else {
                unsigned short* C = (unsigned short*)Cout;   // C^T: [col][row]
                ushort4 pk;
                pk.x = f2bf(acc[fm][fn][0]);
                pk.y = f2bf(acc[fm][fn][1]);
                pk.z = f2bf(acc[fm][fn][2]);
                pk.w = f2bf(acc[fm][fn][3]);
                *(ushort4*)(&C[(size_t)col * 512 + row0]) = pk;
            }
        }
}

// bf16-convert w_v (coalesced) and w_proj^T (coalesced reads, L2-absorbed strided writes)
__global__ __launch_bounds__(256) void prep_w(const float* __restrict__ w_attn,
                                              const float* __restrict__ w_proj,
                                              unsigned short* __restrict__ wv,
                                              unsigned short* __restrict__ wpT)
{
    const int bid = blockIdx.x, tid = threadIdx.x;
    if (bid < 256) {
        const int flat = bid * 256 + tid;        // 65536 = 512*512/4
        const int i = flat >> 7;
        const int m = (flat & 127) * 4;
        float4 v = *(const float4*)(w_attn + (size_t)i * 1536 + 1024 + m);
        ushort4 o;
        o.x = f2bf(v.x); o.y = f2bf(v.y); o.z = f2bf(v.z); o.w = f2bf(v.w);
        *(ushort4*)(wv + (size_t)i * 512 + m) = o;
    } else {
        const int bb = bid - 256;                // 0..15
        const int j  = (bb >> 3) * 256 + tid;
        const int m0 = (bb & 7) * 64;
        #pragma unroll 4
        for (int m = m0; m < m0 + 64; ++m)
            wpT[(size_t)j * 512 + m] = f2bf(w_proj[(size_t)m * 512 + j]);
    }
}

// pass 1: per-(b,chunk of 32 t) column sums of x
__global__ __launch_bounds__(256) void partial_sums(const float* __restrict__ x,
                                                    float* __restrict__ part)
{
    const int bx = blockIdx.x;                   // 256 blocks
    const int b  = bx >> 7;
    const int ch = (bx >> 1) & 63;
    const int j  = (bx & 1) * 256 + threadIdx.x;
    const float* p = x + ((size_t)b * 2048 + ch * 32) * 512 + j;
    float s = 0.f;
    #pragma unroll 8
    for (int t = 0; t < 32; ++t) s += p[(size_t)t * 512];
    part[((size_t)b * 64 + ch) * 512 + j] = s;
}

// pass 2: exclusive scan over the 64 chunks, one wave per (b, column)
__global__ __launch_bounds__(512) void scan_parts(float* __restrict__ part)
{
    const int wid  = blockIdx.x * 8 + (threadIdx.x >> 6);   // 0..1023
    const int lane = threadIdx.x & 63;
    const int b = wid >> 9;
    const int j = wid & 511;
    const size_t idx = ((size_t)b * 64 + lane) * 512 + j;
    float v = part[idx];
    #pragma unroll
    for (int d = 1; d < 64; d <<= 1) {
        float t = __shfl_up(v, d, 64);
        if (lane >= d) v += t;
    }
    float e = __shfl_up(v, 1, 64);
    part[idx] = (lane == 0) ? 0.f : e;
}

// pass 3: s16[b,t,j] = bf16( (prefix + running) / (t+1) )
__global__ __launch_bounds__(256) void finalize(const float* __restrict__ x,
                                                const float* __restrict__ part,
                                                unsigned short* __restrict__ s16)
{
    const int bx = blockIdx.x;
    const int b  = bx >> 7;
    const int ch = (bx >> 1) & 63;
    const int j  = (bx & 1) * 256 + threadIdx.x;
    float run = part[((size_t)b * 64 + ch) * 512 + j];
    const float*    p = x   + ((size_t)b * 2048 + ch * 32) * 512 + j;
    unsigned short* q = s16 + ((size_t)b * 2048 + ch * 32) * 512 + j;
    #pragma unroll 4
    for (int t = 0; t < 32; ++t) {
        run += p[(size_t)t * 512];
        q[(size_t)t * 512] = f2bf(run * (1.0f / (float)(ch * 32 + t + 1)));
    }
}

extern "C" void kernel_launch(void* const* d_in, const int* in_sizes, int n_in,
                              void* d_out, int out_size, void* d_ws, size_t ws_size,
                              hipStream_t stream)
{
    const float* x      = (const float*)d_in[0];   // (2,2048,512)
    const float* w_attn = (const float*)d_in[1];   // (512,1536); V = cols [1024,1536)
    const float* w_proj = (const float*)d_in[2];   // (512,512)
    float* y = (float*)d_out;

    unsigned short* wv  = (unsigned short*)d_ws;       // [512][512] bf16
    unsigned short* wpT = wv  + 512 * 512;             // [512][512] bf16 (w_proj^T)
    unsigned short* wcT = wpT + 512 * 512;             // [512][512] bf16 ((w_v@w_proj)^T)
    unsigned short* s16 = wcT + 512 * 512;             // [4096][512] bf16
    float* part = (float*)(s16 + (size_t)4096 * 512);  // [2][64][512] f32

    prep_w<<<272, 256, 0, stream>>>(w_attn, w_proj, wv, wpT);
    gemm_bf16<1><<<dim3(8, 8), 256, 0, stream>>>(wv, wpT, wcT);       // wcT = (wv@wp)^T
    partial_sums<<<256, 256, 0, stream>>>(x, part);
    scan_parts<<<128, 512, 0, stream>>>(part);
    finalize<<<256, 256, 0, stream>>>(x, part, s16);                  // s = cumsum(x)/(t+1), bf16
    gemm_bf16<0><<<dim3(8, 64), 256, 0, stream>>>(s16, wcT, y);       // y = s @ wc
}

// Round 3
// 25.826 us; speedup vs baseline: 3.2987x; 1.5344x over previous
//
#include <hip/hip_runtime.h>

typedef __bf16 bf16x8 __attribute__((ext_vector_type(8)));
typedef float  f32x4  __attribute__((ext_vector_type(4)));

__device__ __forceinline__ unsigned short f2bf(float f) {
    unsigned int u = __float_as_uint(f);
    u += 0x7FFF + ((u >> 16) & 1);          // round-to-nearest-even
    return (unsigned short)(u >> 16);
}

#define GLD_LDS16(gptr, lptr) \
    __builtin_amdgcn_global_load_lds((const __attribute__((address_space(1))) void*)(gptr), \
                                     (__attribute__((address_space(3))) void*)(lptr), 16, 0, 0)

// ---- 64x64-tile bf16 GEMM body: C[m][n] = sum_k A[m][k]*Bt[n][k], K=512, ld=512.
// EPI=0: Cout=float[M][512] row-major. EPI=1: Cout=bf16 [512][512] transposed (C^T).
template<int EPI>
__device__ __forceinline__ void gemm_tile(const unsigned short* __restrict__ A,
                                          const unsigned short* __restrict__ Bt,
                                          void* __restrict__ Cout,
                                          unsigned short* lds,   // 2*2*4096 ushorts
                                          int bm, int bn)
{
    const int tid  = threadIdx.x;
    const int lane = tid & 63;
    const int w    = tid >> 6;
    const int wm   = w >> 1, wn = w & 1;

    const int srow   = w * 16 + (lane >> 3);
    const int schunk = (lane & 7) ^ (lane >> 3);    // inverse-swizzle on SOURCE
    const unsigned short* gA0 = A  + (size_t)(bm + srow    ) * 512 + schunk * 8;
    const unsigned short* gA1 = A  + (size_t)(bm + srow + 8) * 512 + schunk * 8;
    const unsigned short* gB0 = Bt + (size_t)(bn + srow    ) * 512 + schunk * 8;
    const unsigned short* gB1 = Bt + (size_t)(bn + srow + 8) * 512 + schunk * 8;

    const int arow = lane & 15;
    const int kg   = lane >> 4;
    int offA[2][2], offB[2][2];
    #pragma unroll
    for (int f = 0; f < 2; ++f)
        #pragma unroll
        for (int kk = 0; kk < 2; ++kk) {
            offA[f][kk] = (wm * 32 + f * 16 + arow) * 128 + (((kk * 4 + kg) ^ (arow & 7)) << 4);
            offB[f][kk] = (wn * 32 + f * 16 + arow) * 128 + (((kk * 4 + kg) ^ (arow & 7)) << 4);
        }

    f32x4 acc[2][2] = {};

    auto stage = [&](int buf, int kt) {
        const int k0 = kt * 64;
        unsigned short* la = lds + buf * 8192;
        unsigned short* lb = la + 4096;
        GLD_LDS16(gA0 + k0, la + (w * 16 + 0) * 64);
        GLD_LDS16(gA1 + k0, la + (w * 16 + 8) * 64);
        GLD_LDS16(gB0 + k0, lb + (w * 16 + 0) * 64);
        GLD_LDS16(gB1 + k0, lb + (w * 16 + 8) * 64);
    };

    stage(0, 0);
    asm volatile("s_waitcnt vmcnt(0)" ::: "memory");
    __syncthreads();

    #pragma unroll
    for (int kt = 0; kt < 8; ++kt) {
        const int buf = kt & 1;
        if (kt < 7) stage(buf ^ 1, kt + 1);
        const char* la = (const char*)(lds + buf * 8192);
        const char* lb = la + 8192;
        #pragma unroll
        for (int kk = 0; kk < 2; ++kk) {
            bf16x8 a0 = *(const bf16x8*)(la + offA[0][kk]);
            bf16x8 a1 = *(const bf16x8*)(la + offA[1][kk]);
            bf16x8 b0 = *(const bf16x8*)(lb + offB[0][kk]);
            bf16x8 b1 = *(const bf16x8*)(lb + offB[1][kk]);
            acc[0][0] = __builtin_amdgcn_mfma_f32_16x16x32_bf16(a0, b0, acc[0][0], 0, 0, 0);
            acc[0][1] = __builtin_amdgcn_mfma_f32_16x16x32_bf16(a0, b1, acc[0][1], 0, 0, 0);
            acc[1][0] = __builtin_amdgcn_mfma_f32_16x16x32_bf16(a1, b0, acc[1][0], 0, 0, 0);
            acc[1][1] = __builtin_amdgcn_mfma_f32_16x16x32_bf16(a1, b1, acc[1][1], 0, 0, 0);
        }
        asm volatile("s_waitcnt vmcnt(0)" ::: "memory");
        __syncthreads();
    }

    #pragma unroll
    for (int fm = 0; fm < 2; ++fm)
        #pragma unroll
        for (int fn = 0; fn < 2; ++fn) {
            const int row0 = bm + wm * 32 + fm * 16 + kg * 4;
            const int col  = bn + wn * 32 + fn * 16 + arow;
            if (EPI == 0) {
                float* C = (float*)Cout;
                #pragma unroll
                for (int r = 0; r < 4; ++r)
                    C[(size_t)(row0 + r) * 512 + col] = acc[fm][fn][r];
            } else {
                unsigned short* C = (unsigned short*)Cout;   // C^T
                ushort4 pk;
                pk.x = f2bf(acc[fm][fn][0]);
                pk.y = f2bf(acc[fm][fn][1]);
                pk.z = f2bf(acc[fm][fn][2]);
                pk.w = f2bf(acc[fm][fn][3]);
                *(ushort4*)(&C[(size_t)col * 512 + row0]) = pk;
            }
        }
}

// K1: blocks [0,64)   : LDS-tiled transpose w_proj -> wpT bf16
//     blocks [64,128) : w_attn V-slice -> wv bf16
//     blocks [128,384): partial_sums of x into part
__global__ __launch_bounds__(256) void k1_prep_partial(
    const float* __restrict__ x, const float* __restrict__ w_attn,
    const float* __restrict__ w_proj,
    unsigned short* __restrict__ wv, unsigned short* __restrict__ wpT,
    float* __restrict__ part)
{
    __shared__ float ls[64][65];
    const int bid = blockIdx.x, tid = threadIdx.x;

    if (bid < 64) {
        const int m0 = (bid >> 3) * 64;       // row block of w_proj
        const int j0 = (bid & 7) * 64;        // col block
        const int rr = tid >> 4;              // 0..15
        const int c4 = (tid & 15) * 4;
        #pragma unroll
        for (int i = 0; i < 4; ++i) {
            float4 v = *(const float4*)(w_proj + (size_t)(m0 + rr + 16 * i) * 512 + j0 + c4);
            ls[rr + 16 * i][c4 + 0] = v.x;
            ls[rr + 16 * i][c4 + 1] = v.y;
            ls[rr + 16 * i][c4 + 2] = v.z;
            ls[rr + 16 * i][c4 + 3] = v.w;
        }
        __syncthreads();
        const int c    = tid >> 2;            // 0..63 (j within tile)
        const int mgrp = (tid & 3) * 16;
        #pragma unroll
        for (int u = 0; u < 4; ++u) {
            const int m = mgrp + u * 4;
            ushort4 o;
            o.x = f2bf(ls[m + 0][c]);
            o.y = f2bf(ls[m + 1][c]);
            o.z = f2bf(ls[m + 2][c]);
            o.w = f2bf(ls[m + 3][c]);
            *(ushort4*)(wpT + (size_t)(j0 + c) * 512 + m0 + m) = o;
        }
    } else if (bid < 128) {
        const int bb = bid - 64;
        #pragma unroll
        for (int i = 0; i < 4; ++i) {
            const int flat = bb * 1024 + i * 256 + tid;   // float4 index in [512][128]
            const int ir = flat >> 7;
            const int m4 = (flat & 127) * 4;
            float4 v = *(const float4*)(w_attn + (size_t)ir * 1536 + 1024 + m4);
            ushort4 o;
            o.x = f2bf(v.x); o.y = f2bf(v.y); o.z = f2bf(v.z); o.w = f2bf(v.w);
            *(ushort4*)(wv + (size_t)ir * 512 + m4) = o;
        }
    } else {
        const int bx = bid - 128;             // 0..255
        const int b  = bx >> 7;
        const int ch = (bx >> 1) & 63;
        const int j  = (bx & 1) * 256 + tid;
        const float* p = x + ((size_t)b * 2048 + ch * 32) * 512 + j;
        float s = 0.f;
        #pragma unroll 8
        for (int t = 0; t < 32; ++t) s += p[(size_t)t * 512];
        part[((size_t)b * 64 + ch) * 512 + j] = s;
    }
}

// K2: blocks [0,64)  : small GEMM wcT = (wv @ wp)^T
//     blocks [64,320): finalize (chunk prefix summed from part in-L2) -> s16
__global__ __launch_bounds__(256) void k2_smallgemm_finalize(
    const float* __restrict__ x,
    const unsigned short* __restrict__ wv, const unsigned short* __restrict__ wpT,
    const float* __restrict__ part,
    unsigned short* __restrict__ wcT, unsigned short* __restrict__ s16)
{
    __shared__ unsigned short lds[2 * 2 * 4096];
    const int bid = blockIdx.x, tid = threadIdx.x;

    if (bid < 64) {
        gemm_tile<1>(wv, wpT, wcT, lds, (bid >> 3) * 64, (bid & 7) * 64);
    } else {
        const int bx = bid - 64;              // 0..255
        const int b  = bx >> 7;
        const int ch = (bx >> 1) & 63;
        const int j  = (bx & 1) * 256 + tid;
        float run = 0.f;
        #pragma unroll 8
        for (int c = 0; c < ch; ++c)
            run += part[((size_t)b * 64 + c) * 512 + j];
        const float*    p = x   + ((size_t)b * 2048 + ch * 32) * 512 + j;
        unsigned short* q = s16 + ((size_t)b * 2048 + ch * 32) * 512 + j;
        #pragma unroll 4
        for (int t = 0; t < 32; ++t) {
            run += p[(size_t)t * 512];
            q[(size_t)t * 512] = f2bf(run * (1.0f / (float)(ch * 32 + t + 1)));
        }
    }
}

// K3: y = s16 @ wcT^T  (4096x512x512), XCD-chunked swizzle over 512 blocks
__global__ __launch_bounds__(256) void k3_biggemm(
    const unsigned short* __restrict__ s16,
    const unsigned short* __restrict__ wcT,
    float* __restrict__ y)
{
    __shared__ unsigned short lds[2 * 2 * 4096];
    const int bid  = blockIdx.x;            // 0..511
    const int xcd  = bid & 7;
    const int idx  = bid >> 3;              // 0..63
    const int vy   = xcd * 8 + (idx >> 3);  // m-tile 0..63
    const int vx   = idx & 7;               // n-tile 0..7
    gemm_tile<0>(s16, wcT, y, lds, vy * 64, vx * 64);
}

extern "C" void kernel_launch(void* const* d_in, const int* in_sizes, int n_in,
                              void* d_out, int out_size, void* d_ws, size_t ws_size,
                              hipStream_t stream)
{
    const float* x      = (const float*)d_in[0];   // (2,2048,512)
    const float* w_attn = (const float*)d_in[1];   // (512,1536); V = cols [1024,1536)
    const float* w_proj = (const float*)d_in[2];   // (512,512)
    float* y = (float*)d_out;

    unsigned short* wv  = (unsigned short*)d_ws;       // [512][512] bf16
    unsigned short* wpT = wv  + 512 * 512;             // [512][512] bf16 (w_proj^T)
    unsigned short* wcT = wpT + 512 * 512;             // [512][512] bf16 ((wv@wp)^T)
    unsigned short* s16 = wcT + 512 * 512;             // [4096][512] bf16
    float* part = (float*)(s16 + (size_t)4096 * 512);  // [2][64][512] f32

    k1_prep_partial<<<384, 256, 0, stream>>>(x, w_attn, w_proj, wv, wpT, part);
    k2_smallgemm_finalize<<<320, 256, 0, stream>>>(x, wv, wpT, part, wcT, s16);
    k3_biggemm<<<512, 256, 0, stream>>>(s16, wcT, y);
}